// Round 13
// baseline (332.193 us; speedup 1.0000x reference)
//
#include <hip/hip_runtime.h>
#include <hip/hip_bf16.h>

// OddOneOutNet forward: B=1024, N=5, H=W=64, D=24, NK=6, META=16.
// Inputs fp32, output fp32.
// Kernel A (R13): R12 CNN + conv1 rewritten over channel-PAIRS with float2
//   arithmetic (targets v_pk_fma_f32: 2 fp32 FMA/instr, halves conv1 issue)
//   + __launch_bounds__(256,6) (VGPR cap 85; LDS then limits at 5 blocks/CU).
// Kernel B: head, R7/R10 verbatim (chain-latency-bound at 1 chain/SIMD).

typedef __attribute__((ext_vector_type(8))) short bf16x8;   // 8 bf16 = 4 VGPRs
typedef __attribute__((ext_vector_type(4))) float f32x4;

static __device__ __forceinline__ unsigned short f2bfu(float f) {
    return __bfloat16_as_ushort(__float2bfloat16(f));
}

// LDS: phase1 inBuf fp32 66x66 = 17,424 B
//      phase2 h1 bf16 [34][34][8] = 18,496 B (aliases inBuf)
//             h2 bf16 [18][18][16] at +18,496 = 10,368 B (disjoint from inBuf)
union CnnLds {
    float inBuf[66 * 66];
    unsigned short h1h2[34 * 34 * 8 + 18 * 18 * 16];   // h1 @0, h2 @9248 (shorts)
};

__global__ __launch_bounds__(256, 6)
void cnn_panel_kernel(const float* __restrict__ xin,   // [BN,64,64]
                      const float* __restrict__ c1w, const float* __restrict__ c1b,
                      const float* __restrict__ c2w, const float* __restrict__ c2b,
                      const float* __restrict__ c3w, const float* __restrict__ c3b,
                      float* __restrict__ pooled)      // [BN,16] (ws)
{
    __shared__ CnnLds U;
    float* const inBuf = U.inBuf;
    unsigned short* const h1 = U.h1h2;           // [y][x][ci], 34x34x8
    unsigned short* const h2 = U.h1h2 + 9248;    // [y][x][ci], 18x18x16

    const int tid = threadIdx.x;
    const int img = blockIdx.x;
    const int lane = tid & 63, wave = tid >> 6;

    // ---- issue panel loads FIRST (latency hidden behind zeroing) ----
    float4 pan[4];
    {
        const float4* xv = (const float4*)(xin + (size_t)img * 4096);
        #pragma unroll
        for (int p = 0; p < 4; ++p) pan[p] = xv[tid + (p << 8)];
    }

    // ---- zero inBuf halo ring (260 cells) + all of h2 (disjoint from inBuf) ----
    if (tid < 260) {
        int y, x;
        if (tid < 66)       { y = 0;         x = tid; }
        else if (tid < 132) { y = 65;        x = tid - 66; }
        else if (tid < 196) { y = tid - 131; x = 0; }      // rows 1..64
        else                { y = tid - 195; x = 65; }
        inBuf[y * 66 + x] = 0.0f;
    }
    for (int i = tid; i < (18 * 18 * 16) / 8; i += 256)
        ((uint4*)h2)[i] = make_uint4(0, 0, 0, 0);
    __syncthreads();

    // ---- store panel into padded inBuf interior ----
    #pragma unroll
    for (int p = 0; p < 4; ++p) {
        int i = tid + (p << 8);
        int base = i << 2, y = base >> 6, x = base & 63;
        float* dst = &inBuf[(y + 1) * 66 + (x + 1)];
        dst[0] = pan[p].x; dst[1] = pan[p].y; dst[2] = pan[p].z; dst[3] = pan[p].w;
    }
    __syncthreads();

    // ---- conv1(1->8,3x3,SAME)+relu+maxpool2, channel-PAIRED (v_pk_fma_f32) ----
    float c1out[4][8];
    #pragma unroll
    for (int p = 0; p < 4; ++p) {
        int pos = tid + (p << 8);
        int py = pos >> 5, px = pos & 31;
        float patch[4][4];
        #pragma unroll
        for (int dy = 0; dy < 4; ++dy)
            #pragma unroll
            for (int dx = 0; dx < 4; ++dx)
                patch[dy][dx] = inBuf[(2 * py + dy) * 66 + (2 * px + dx)];
        #pragma unroll
        for (int cp = 0; cp < 4; ++cp) {
            float2 bb = make_float2(c1b[2 * cp], c1b[2 * cp + 1]);
            float2 m = make_float2(-1e30f, -1e30f);
            #pragma unroll
            for (int ay = 0; ay < 2; ++ay)
                #pragma unroll
                for (int ax = 0; ax < 2; ++ax) {
                    float2 acc = bb;
                    #pragma unroll
                    for (int ky = 0; ky < 3; ++ky)
                        #pragma unroll
                        for (int kx = 0; kx < 3; ++kx) {
                            float pv = patch[ay + ky][ax + kx];
                            float2 w = make_float2(c1w[(2 * cp) * 9 + ky * 3 + kx],
                                                   c1w[(2 * cp + 1) * 9 + ky * 3 + kx]);
                            acc += make_float2(pv, pv) * w;   // <2 x float> -> v_pk_fma_f32
                        }
                    m.x = fmaxf(m.x, acc.x);
                    m.y = fmaxf(m.y, acc.y);
                }
            c1out[p][2 * cp]     = fmaxf(m.x, 0.0f);
            c1out[p][2 * cp + 1] = fmaxf(m.y, 0.0f);
        }
    }
    __syncthreads();   // inBuf reads done; safe to overwrite as h1

    // ---- write h1 interior (8 bf16 packed = 1 ds_write_b128) + halo zeros ----
    #pragma unroll
    for (int p = 0; p < 4; ++p) {
        int pos = tid + (p << 8);
        int py = pos >> 5, px = pos & 31;
        uint4 v;
        v.x = (unsigned)f2bfu(c1out[p][0]) | ((unsigned)f2bfu(c1out[p][1]) << 16);
        v.y = (unsigned)f2bfu(c1out[p][2]) | ((unsigned)f2bfu(c1out[p][3]) << 16);
        v.z = (unsigned)f2bfu(c1out[p][4]) | ((unsigned)f2bfu(c1out[p][5]) << 16);
        v.w = (unsigned)f2bfu(c1out[p][6]) | ((unsigned)f2bfu(c1out[p][7]) << 16);
        *(uint4*)&h1[((py + 1) * 34 + (px + 1)) * 8] = v;
    }
    if (tid < 132) {   // halo: 34x34 - 32x32 = 132 positions x 16 B
        int r = tid, y, x;
        if (r < 34)       { y = 0;      x = r; }
        else if (r < 68)  { y = 33;     x = r - 34; }
        else if (r < 100) { y = r - 67; x = 0; }
        else              { y = r - 99; x = 33; }
        *(uint4*)&h1[(y * 34 + x) * 8] = make_uint4(0, 0, 0, 0);
    }

    // ---- conv2 B-frags + per-lane tap offsets (registers, no LDS) ----
    const int q = lane >> 4, mA = lane & 15, oc = lane & 15;
    int ky2[3], kx2[3];
    bf16x8 b2f[3];
    #pragma unroll
    for (int s = 0; s < 3; ++s) {
        int t = 4 * s + q;
        int tt = (t > 8) ? 4 : t;
        ky2[s] = tt / 3; kx2[s] = tt % 3;
        union { unsigned short us[8]; bf16x8 v; } bb;
        #pragma unroll
        for (int j = 0; j < 8; ++j)
            bb.us[j] = (t <= 8 && oc < 12) ? f2bfu(c2w[(oc * 8 + j) * 9 + t])
                                           : (unsigned short)0;
        b2f[s] = bb.v;
    }
    const float bias2 = (oc < 12) ? c2b[oc] : 0.0f;
    __syncthreads();

    // ---- conv2 via MFMA + fused maxpool -> h2 interior ----
    for (int h = 0; h < 2; ++h) {
        #pragma unroll
        for (int Yi = 0; Yi < 4; ++Yi) {
            int Y = wave * 4 + Yi;
            float m0 = -1e30f, m1 = -1e30f;
            #pragma unroll
            for (int half = 0; half < 2; ++half) {
                int y = 2 * Y + half;
                f32x4 acc = {bias2, bias2, bias2, bias2};
                #pragma unroll
                for (int s = 0; s < 3; ++s) {
                    int off = ((y + ky2[s]) * 34 + (h * 16 + mA + kx2[s])) * 8;
                    bf16x8 a = *(const bf16x8*)&h1[off];
                    acc = __builtin_amdgcn_mfma_f32_16x16x32_bf16(a, b2f[s], acc, 0, 0, 0);
                }
                m0 = fmaxf(m0, fmaxf(acc[0], acc[1]));
                m1 = fmaxf(m1, fmaxf(acc[2], acc[3]));
            }
            if (oc < 12) {
                int X0 = h * 8 + q * 2;
                h2[((Y + 1) * 18 + (X0 + 1)) * 16 + oc] = f2bfu(fmaxf(m0, 0.0f));
                h2[((Y + 1) * 18 + (X0 + 2)) * 16 + oc] = f2bfu(fmaxf(m1, 0.0f));
            }
        }
    }
    __syncthreads();

    // ---- conv3 via MFMA + relu + mean -> pooled[img][16] ----
    {
        const int hhalf = q & 1, tq = q >> 1;
        int ky3[5], kx3[5];
        bf16x8 b3f[5];
        #pragma unroll
        for (int s = 0; s < 5; ++s) {
            int slot = 2 * s + tq;
            int tt = (slot > 8) ? 4 : slot;
            ky3[s] = tt / 3; kx3[s] = tt % 3;
            union { unsigned short us[8]; bf16x8 v; } bb;
            #pragma unroll
            for (int j = 0; j < 8; ++j) {
                int ci = hhalf * 8 + j;
                bb.us[j] = (slot <= 8 && ci < 12) ? f2bfu(c3w[(oc * 12 + ci) * 9 + slot])
                                                  : (unsigned short)0;
            }
            b3f[s] = bb.v;
        }
        const float bias3 = c3b[oc];
        float psum = 0.0f;
        #pragma unroll
        for (int Yi = 0; Yi < 4; ++Yi) {
            int y = wave * 4 + Yi;
            f32x4 acc = {bias3, bias3, bias3, bias3};
            #pragma unroll
            for (int s = 0; s < 5; ++s) {
                int off = ((y + ky3[s]) * 18 + (mA + kx3[s])) * 16 + hhalf * 8;
                bf16x8 a = *(const bf16x8*)&h2[off];
                acc = __builtin_amdgcn_mfma_f32_16x16x32_bf16(a, b3f[s], acc, 0, 0, 0);
            }
            psum += fmaxf(acc[0], 0.0f) + fmaxf(acc[1], 0.0f)
                  + fmaxf(acc[2], 0.0f) + fmaxf(acc[3], 0.0f);
        }
        psum += __shfl_down(psum, 32);
        psum += __shfl_down(psum, 16);
        float* red = (float*)h1;
        if (lane < 16) red[lane * 4 + wave] = psum;
        __syncthreads();
        if (tid < 16) {
            float s = red[tid * 4] + red[tid * 4 + 1] + red[tid * 4 + 2] + red[tid * 4 + 3];
            pooled[(size_t)img * 16 + tid] = s * (1.0f / 256.0f);
        }
    }
}

// ---------------------------------------------------------------------------
// Kernel B: head (R7/R10 verbatim). 256-thr blocks, 4 waves, ONE WAVE PER ROW.
// ---------------------------------------------------------------------------
struct RowS {
    float ph[5][16], mt[5][16];
    float zc[5][20], zmh[5][12], zm[5][12];
    float p1h[5][24], h0[5][24];
    float archl[5][6], q[5][6];
    float center[5][24], coord[5][24], x0[5][24];
    float qkv[5][72];
    float attn[2][5][5];
    float amix[5][24], aout[5][24], x1[5][24];
    float ffh[5][48], ff2o[5][24], hset[5][24], mo[5][24];
    float pq[20], pdist[20];
    float relh[20][10], relo[20][10];
    float rmean[5][10], rmax[5][10];
    float sfeat[5][146];
    float s1h[5][40];
};

__global__ __launch_bounds__(256)
void head_kernel(const float* __restrict__ pooled,    // [B*5,16]
                 const float* __restrict__ meta,      // [B,5,16]
                 const float* __restrict__ enc_fc_w, const float* __restrict__ enc_fc_b,
                 const float* __restrict__ m1_w, const float* __restrict__ m1_b,
                 const float* __restrict__ m2_w, const float* __restrict__ m2_b,
                 const float* __restrict__ p1_w, const float* __restrict__ p1_b,
                 const float* __restrict__ p2_w, const float* __restrict__ p2_b,
                 const float* __restrict__ centers,
                 const float* __restrict__ arch_w, const float* __restrict__ arch_b,
                 const float* __restrict__ in_proj_w, const float* __restrict__ in_proj_b,
                 const float* __restrict__ out_proj_w, const float* __restrict__ out_proj_b,
                 const float* __restrict__ ln1_g, const float* __restrict__ ln1_b,
                 const float* __restrict__ ff1_w, const float* __restrict__ ff1_b,
                 const float* __restrict__ ff2_w, const float* __restrict__ ff2_b,
                 const float* __restrict__ ln2_g, const float* __restrict__ ln2_b,
                 const float* __restrict__ rel1_w, const float* __restrict__ rel1_b,
                 const float* __restrict__ rel2_w, const float* __restrict__ rel2_b,
                 const float* __restrict__ s1_w, const float* __restrict__ s1_b,
                 const float* __restrict__ s2_w, const float* __restrict__ s2_b,
                 float* __restrict__ out, int q_off, int Bb)
{
    __shared__ RowS S[4];

    const int tid  = threadIdx.x;
    const int wid  = tid >> 6;
    const int lane = tid & 63;
    const int row  = blockIdx.x * 4 + wid;
    if (row >= Bb) return;

    RowS& H = S[wid];

    for (int i = lane; i < 80; i += 64) ((float*)H.ph)[i] = pooled[(size_t)row * 80 + i];
    for (int i = lane; i < 80; i += 64) ((float*)H.mt)[i] = meta[(size_t)row * 80 + i];

    for (int idx = lane; idx < 100; idx += 64) {
        int n = idx / 20, o = idx % 20;
        float a = enc_fc_b[o];
        #pragma unroll
        for (int k = 0; k < 16; ++k) a += H.ph[n][k] * enc_fc_w[o * 16 + k];
        H.zc[n][o] = a;
    }
    for (int idx = lane; idx < 60; idx += 64) {
        int n = idx / 12, o = idx % 12;
        float a = m1_b[o];
        #pragma unroll
        for (int k = 0; k < 16; ++k) a += H.mt[n][k] * m1_w[o * 16 + k];
        H.zmh[n][o] = fmaxf(a, 0.0f);
    }
    for (int idx = lane; idx < 60; idx += 64) {
        int n = idx / 12, o = idx % 12;
        float a = m2_b[o];
        #pragma unroll
        for (int k = 0; k < 12; ++k) a += H.zmh[n][k] * m2_w[o * 12 + k];
        H.zm[n][o] = a;
    }
    for (int idx = lane; idx < 120; idx += 64) {
        int n = idx / 24, o = idx % 24;
        float a = p1_b[o];
        #pragma unroll
        for (int k = 0; k < 20; ++k) a += H.zc[n][k] * p1_w[o * 32 + k];
        #pragma unroll
        for (int k = 0; k < 12; ++k) a += H.zm[n][k] * p1_w[o * 32 + 20 + k];
        H.p1h[n][o] = fmaxf(a, 0.0f);
    }
    for (int idx = lane; idx < 120; idx += 64) {
        int n = idx / 24, o = idx % 24;
        float a = p2_b[o];
        #pragma unroll
        for (int k = 0; k < 24; ++k) a += H.p1h[n][k] * p2_w[o * 24 + k];
        H.h0[n][o] = a;
    }
    for (int idx = lane; idx < 30; idx += 64) {
        int n = idx / 6, o = idx % 6;
        float a = arch_b[o];
        #pragma unroll
        for (int k = 0; k < 24; ++k) a += H.h0[n][k] * arch_w[o * 24 + k];
        H.archl[n][o] = a;
    }
    if (lane < 5) {
        int n = lane;
        float m = H.archl[n][0];
        #pragma unroll
        for (int k = 1; k < 6; ++k) m = fmaxf(m, H.archl[n][k]);
        float e[6], s = 0.0f;
        #pragma unroll
        for (int k = 0; k < 6; ++k) { e[k] = __expf(H.archl[n][k] - m); s += e[k]; }
        float inv = 1.0f / s;
        #pragma unroll
        for (int k = 0; k < 6; ++k) H.q[n][k] = e[k] * inv;
    }
    for (int idx = lane; idx < 120; idx += 64) {
        int n = idx / 24, d = idx % 24;
        float a = 0.0f;
        #pragma unroll
        for (int k = 0; k < 6; ++k) a += H.q[n][k] * centers[k * 24 + d];
        H.center[n][d] = a;
        H.coord[n][d] = H.h0[n][d] - a;
        H.x0[n][d] = H.h0[n][d] + a;
    }
    for (int idx = lane; idx < 360; idx += 64) {
        int n = idx / 72, o = idx % 72;
        float a = in_proj_b[o];
        #pragma unroll
        for (int k = 0; k < 24; ++k) a += H.x0[n][k] * in_proj_w[o * 24 + k];
        H.qkv[n][o] = a;
    }
    if (lane < 10) {
        int h = lane / 5, i = lane % 5;
        const float scale = 0.28867513459481287f;  // 1/sqrt(12)
        float sc[5], m = -1e30f;
        for (int j = 0; j < 5; ++j) {
            float a = 0.0f;
            #pragma unroll
            for (int d = 0; d < 12; ++d) a += H.qkv[i][h * 12 + d] * H.qkv[j][24 + h * 12 + d];
            sc[j] = a * scale;
            m = fmaxf(m, sc[j]);
        }
        float s = 0.0f;
        #pragma unroll
        for (int j = 0; j < 5; ++j) { sc[j] = __expf(sc[j] - m); s += sc[j]; }
        float inv = 1.0f / s;
        #pragma unroll
        for (int j = 0; j < 5; ++j) H.attn[h][i][j] = sc[j] * inv;
    }
    for (int idx = lane; idx < 120; idx += 64) {
        int i = idx / 24, o = idx % 24;
        int h = o / 12, d = o % 12;
        float a = 0.0f;
        #pragma unroll
        for (int j = 0; j < 5; ++j) a += H.attn[h][i][j] * H.qkv[j][48 + h * 12 + d];
        H.amix[i][o] = a;
    }
    for (int idx = lane; idx < 120; idx += 64) {
        int n = idx / 24, o = idx % 24;
        float a = out_proj_b[o];
        #pragma unroll
        for (int k = 0; k < 24; ++k) a += H.amix[n][k] * out_proj_w[o * 24 + k];
        H.aout[n][o] = H.x0[n][o] + a;
    }
    if (lane < 5) {
        int n = lane;
        float m = 0.0f;
        #pragma unroll
        for (int k = 0; k < 24; ++k) m += H.aout[n][k];
        m *= (1.0f / 24.0f);
        float v = 0.0f;
        #pragma unroll
        for (int k = 0; k < 24; ++k) { float d = H.aout[n][k] - m; v += d * d; }
        v *= (1.0f / 24.0f);
        float inv = 1.0f / sqrtf(v + 1e-5f);
        #pragma unroll
        for (int k = 0; k < 24; ++k)
            H.x1[n][k] = (H.aout[n][k] - m) * inv * ln1_g[k] + ln1_b[k];
    }
    for (int idx = lane; idx < 240; idx += 64) {
        int n = idx / 48, o = idx % 48;
        float a = ff1_b[o];
        #pragma unroll
        for (int k = 0; k < 24; ++k) a += H.x1[n][k] * ff1_w[o * 24 + k];
        H.ffh[n][o] = fmaxf(a, 0.0f);
    }
    for (int idx = lane; idx < 120; idx += 64) {
        int n = idx / 24, o = idx % 24;
        float a = ff2_b[o];
        #pragma unroll
        for (int k = 0; k < 48; ++k) a += H.ffh[n][k] * ff2_w[o * 48 + k];
        H.ff2o[n][o] = H.x1[n][o] + a;
    }
    if (lane < 5) {
        int n = lane;
        float m = 0.0f;
        #pragma unroll
        for (int k = 0; k < 24; ++k) m += H.ff2o[n][k];
        m *= (1.0f / 24.0f);
        float v = 0.0f;
        #pragma unroll
        for (int k = 0; k < 24; ++k) { float d = H.ff2o[n][k] - m; v += d * d; }
        v *= (1.0f / 24.0f);
        float inv = 1.0f / sqrtf(v + 1e-5f);
        #pragma unroll
        for (int k = 0; k < 24; ++k)
            H.hset[n][k] = (H.ff2o[n][k] - m) * inv * ln2_g[k] + ln2_b[k];
    }
    for (int idx = lane; idx < 120; idx += 64) {
        int n = idx / 24, d = idx % 24;
        float s = H.hset[0][d] + H.hset[1][d] + H.hset[2][d] + H.hset[3][d] + H.hset[4][d];
        H.mo[n][d] = (s - H.hset[n][d]) * 0.25f;
    }
    if (lane < 20) {
        int i = lane / 4, jj = lane % 4;
        int j = jj + (jj >= i ? 1 : 0);
        float qo = 0.0f;
        #pragma unroll
        for (int k = 0; k < 6; ++k) qo += H.q[i][k] * H.q[j][k];
        H.pq[lane] = qo;
        float d2 = 0.0f;
        #pragma unroll
        for (int k = 0; k < 24; ++k) { float d = H.coord[i][k] - H.coord[j][k]; d2 += d * d; }
        H.pdist[lane] = (d2 > 0.0f) ? sqrtf(d2) : 0.0f;
    }
    for (int idx = lane; idx < 200; idx += 64) {
        int p = idx / 10, c = idx % 10;
        int i = p / 4, jj = p % 4;
        int j = jj + (jj >= i ? 1 : 0);
        float a = rel1_b[c];
        const float* wr = rel1_w + c * 74;
        #pragma unroll
        for (int k = 0; k < 24; ++k) a += H.hset[i][k] * wr[k];
        #pragma unroll
        for (int k = 0; k < 24; ++k) a += H.hset[j][k] * wr[24 + k];
        #pragma unroll
        for (int k = 0; k < 24; ++k) a += fabsf(H.coord[i][k] - H.coord[j][k]) * wr[48 + k];
        a += H.pq[p] * wr[72];
        a += H.pdist[p] * wr[73];
        H.relh[p][c] = fmaxf(a, 0.0f);
    }
    for (int idx = lane; idx < 200; idx += 64) {
        int p = idx / 10, c = idx % 10;
        float a = rel2_b[c];
        #pragma unroll
        for (int k = 0; k < 10; ++k) a += H.relh[p][k] * rel2_w[c * 10 + k];
        H.relo[p][c] = fmaxf(a, 0.0f);
    }
    for (int idx = lane; idx < 50; idx += 64) {
        int i = idx / 10, c = idx % 10;
        float s = 0.0f, m = -1e30f;
        #pragma unroll
        for (int jj = 0; jj < 4; ++jj) {
            float v = H.relo[i * 4 + jj][c];
            s += v; m = fmaxf(m, v);
        }
        H.rmean[i][c] = s * 0.25f;
        H.rmax[i][c] = m;
    }
    for (int idx = lane; idx < 730; idx += 64) {
        int n = idx / 146, k = idx % 146;
        float v;
        if (k < 24)       v = H.h0[n][k];
        else if (k < 48)  v = H.hset[n][k - 24];
        else if (k < 72)  v = H.center[n][k - 48];
        else if (k < 96)  v = H.coord[n][k - 72];
        else if (k < 120) v = fabsf(H.hset[n][k - 96] - H.mo[n][k - 96]);
        else if (k < 130) v = H.rmean[n][k - 120];
        else if (k < 140) v = H.rmax[n][k - 130];
        else              v = H.q[n][k - 140];
        H.sfeat[n][k] = v;
    }
    for (int idx = lane; idx < 200; idx += 64) {
        int n = idx / 40, o = idx % 40;
        float a = s1_b[o];
        #pragma unroll 8
        for (int k = 0; k < 146; ++k) a += H.sfeat[n][k] * s1_w[o * 146 + k];
        H.s1h[n][o] = fmaxf(a, 0.0f);
    }
    if (lane < 5) {
        int n = lane;
        float a = s2_b[0];
        #pragma unroll
        for (int k = 0; k < 40; ++k) a += H.s1h[n][k] * s2_w[k];
        out[(size_t)row * 5 + n] = a;
    }
    if (lane < 30) {
        out[q_off + (size_t)row * 30 + lane] = H.q[lane / 6][lane % 6];
    }
}

extern "C" void kernel_launch(void* const* d_in, const int* in_sizes, int n_in,
                              void* d_out, int out_size, void* d_ws, size_t ws_size,
                              hipStream_t stream) {
    const int BN = in_sizes[0] / (64 * 64);   // B*5
    const int Bb = BN / 5;                    // B

    float* pooled = (float*)d_ws;             // [BN][16] fp32

    cnn_panel_kernel<<<BN, 256, 0, stream>>>(
        (const float*)d_in[0],
        (const float*)d_in[2], (const float*)d_in[3],
        (const float*)d_in[4], (const float*)d_in[5],
        (const float*)d_in[6], (const float*)d_in[7],
        pooled);

    head_kernel<<<(Bb + 3) / 4, 256, 0, stream>>>(
        pooled, (const float*)d_in[1],
        (const float*)d_in[8], (const float*)d_in[9],
        (const float*)d_in[10], (const float*)d_in[11],
        (const float*)d_in[12], (const float*)d_in[13],
        (const float*)d_in[14], (const float*)d_in[15],
        (const float*)d_in[16], (const float*)d_in[17],
        (const float*)d_in[18],
        (const float*)d_in[19], (const float*)d_in[20],
        (const float*)d_in[21], (const float*)d_in[22],
        (const float*)d_in[23], (const float*)d_in[24],
        (const float*)d_in[25], (const float*)d_in[26],
        (const float*)d_in[27], (const float*)d_in[28],
        (const float*)d_in[29], (const float*)d_in[30],
        (const float*)d_in[31], (const float*)d_in[32],
        (const float*)d_in[33], (const float*)d_in[34],
        (const float*)d_in[35], (const float*)d_in[36],
        (const float*)d_in[37], (const float*)d_in[38],
        (const float*)d_in[39], (const float*)d_in[40],
        (float*)d_out, BN, Bb);
}

// Round 14
// 314.513 us; speedup vs baseline: 1.0562x; 1.0562x over previous
//
#include <hip/hip_runtime.h>
#include <hip/hip_bf16.h>

// OddOneOutNet forward: B=1024, N=5, H=W=64, D=24, NK=6, META=16.
// Inputs fp32, output fp32.
// Kernel A (R14): conv1 channel-paired float2 (v_pk_fma_f32, R13-proven:
//   VALUBusy 62->46%) + __launch_bounds__(256,4) (R12-proven: VGPR 64,
//   occupancy 43% -- (256,6) regressed to 30.7% because AGPRs share the
//   unified file and the reported VGPR count undercounts true usage).
// Kernel B: head, R7/R10 verbatim (chain-latency-bound at 1 chain/SIMD).

typedef __attribute__((ext_vector_type(8))) short bf16x8;   // 8 bf16 = 4 VGPRs
typedef __attribute__((ext_vector_type(4))) float f32x4;

static __device__ __forceinline__ unsigned short f2bfu(float f) {
    return __bfloat16_as_ushort(__float2bfloat16(f));
}

// LDS: phase1 inBuf fp32 66x66 = 17,424 B
//      phase2 h1 bf16 [34][34][8] = 18,496 B (aliases inBuf)
//             h2 bf16 [18][18][16] at +18,496 = 10,368 B (disjoint from inBuf)
union CnnLds {
    float inBuf[66 * 66];
    unsigned short h1h2[34 * 34 * 8 + 18 * 18 * 16];   // h1 @0, h2 @9248 (shorts)
};

__global__ __launch_bounds__(256, 4)
void cnn_panel_kernel(const float* __restrict__ xin,   // [BN,64,64]
                      const float* __restrict__ c1w, const float* __restrict__ c1b,
                      const float* __restrict__ c2w, const float* __restrict__ c2b,
                      const float* __restrict__ c3w, const float* __restrict__ c3b,
                      float* __restrict__ pooled)      // [BN,16] (ws)
{
    __shared__ CnnLds U;
    float* const inBuf = U.inBuf;
    unsigned short* const h1 = U.h1h2;           // [y][x][ci], 34x34x8
    unsigned short* const h2 = U.h1h2 + 9248;    // [y][x][ci], 18x18x16

    const int tid = threadIdx.x;
    const int img = blockIdx.x;
    const int lane = tid & 63, wave = tid >> 6;

    // ---- issue panel loads FIRST (latency hidden behind zeroing) ----
    float4 pan[4];
    {
        const float4* xv = (const float4*)(xin + (size_t)img * 4096);
        #pragma unroll
        for (int p = 0; p < 4; ++p) pan[p] = xv[tid + (p << 8)];
    }

    // ---- zero inBuf halo ring (260 cells) + all of h2 (disjoint from inBuf) ----
    if (tid < 260) {
        int y, x;
        if (tid < 66)       { y = 0;         x = tid; }
        else if (tid < 132) { y = 65;        x = tid - 66; }
        else if (tid < 196) { y = tid - 131; x = 0; }      // rows 1..64
        else                { y = tid - 195; x = 65; }
        inBuf[y * 66 + x] = 0.0f;
    }
    for (int i = tid; i < (18 * 18 * 16) / 8; i += 256)
        ((uint4*)h2)[i] = make_uint4(0, 0, 0, 0);
    __syncthreads();

    // ---- store panel into padded inBuf interior ----
    #pragma unroll
    for (int p = 0; p < 4; ++p) {
        int i = tid + (p << 8);
        int base = i << 2, y = base >> 6, x = base & 63;
        float* dst = &inBuf[(y + 1) * 66 + (x + 1)];
        dst[0] = pan[p].x; dst[1] = pan[p].y; dst[2] = pan[p].z; dst[3] = pan[p].w;
    }
    __syncthreads();

    // ---- conv1(1->8,3x3,SAME)+relu+maxpool2, channel-PAIRED (v_pk_fma_f32) ----
    float c1out[4][8];
    #pragma unroll
    for (int p = 0; p < 4; ++p) {
        int pos = tid + (p << 8);
        int py = pos >> 5, px = pos & 31;
        float patch[4][4];
        #pragma unroll
        for (int dy = 0; dy < 4; ++dy)
            #pragma unroll
            for (int dx = 0; dx < 4; ++dx)
                patch[dy][dx] = inBuf[(2 * py + dy) * 66 + (2 * px + dx)];
        #pragma unroll
        for (int cp = 0; cp < 4; ++cp) {
            float2 bb = make_float2(c1b[2 * cp], c1b[2 * cp + 1]);
            float2 m = make_float2(-1e30f, -1e30f);
            #pragma unroll
            for (int ay = 0; ay < 2; ++ay)
                #pragma unroll
                for (int ax = 0; ax < 2; ++ax) {
                    float2 acc = bb;
                    #pragma unroll
                    for (int ky = 0; ky < 3; ++ky)
                        #pragma unroll
                        for (int kx = 0; kx < 3; ++kx) {
                            float pv = patch[ay + ky][ax + kx];
                            float2 w = make_float2(c1w[(2 * cp) * 9 + ky * 3 + kx],
                                                   c1w[(2 * cp + 1) * 9 + ky * 3 + kx]);
                            acc += make_float2(pv, pv) * w;   // <2 x float> -> v_pk_fma_f32
                        }
                    m.x = fmaxf(m.x, acc.x);
                    m.y = fmaxf(m.y, acc.y);
                }
            c1out[p][2 * cp]     = fmaxf(m.x, 0.0f);
            c1out[p][2 * cp + 1] = fmaxf(m.y, 0.0f);
        }
    }
    __syncthreads();   // inBuf reads done; safe to overwrite as h1

    // ---- write h1 interior (8 bf16 packed = 1 ds_write_b128) + halo zeros ----
    #pragma unroll
    for (int p = 0; p < 4; ++p) {
        int pos = tid + (p << 8);
        int py = pos >> 5, px = pos & 31;
        uint4 v;
        v.x = (unsigned)f2bfu(c1out[p][0]) | ((unsigned)f2bfu(c1out[p][1]) << 16);
        v.y = (unsigned)f2bfu(c1out[p][2]) | ((unsigned)f2bfu(c1out[p][3]) << 16);
        v.z = (unsigned)f2bfu(c1out[p][4]) | ((unsigned)f2bfu(c1out[p][5]) << 16);
        v.w = (unsigned)f2bfu(c1out[p][6]) | ((unsigned)f2bfu(c1out[p][7]) << 16);
        *(uint4*)&h1[((py + 1) * 34 + (px + 1)) * 8] = v;
    }
    if (tid < 132) {   // halo: 34x34 - 32x32 = 132 positions x 16 B
        int r = tid, y, x;
        if (r < 34)       { y = 0;      x = r; }
        else if (r < 68)  { y = 33;     x = r - 34; }
        else if (r < 100) { y = r - 67; x = 0; }
        else              { y = r - 99; x = 33; }
        *(uint4*)&h1[(y * 34 + x) * 8] = make_uint4(0, 0, 0, 0);
    }

    // ---- conv2 B-frags + per-lane tap offsets (registers, no LDS) ----
    const int q = lane >> 4, mA = lane & 15, oc = lane & 15;
    int ky2[3], kx2[3];
    bf16x8 b2f[3];
    #pragma unroll
    for (int s = 0; s < 3; ++s) {
        int t = 4 * s + q;
        int tt = (t > 8) ? 4 : t;
        ky2[s] = tt / 3; kx2[s] = tt % 3;
        union { unsigned short us[8]; bf16x8 v; } bb;
        #pragma unroll
        for (int j = 0; j < 8; ++j)
            bb.us[j] = (t <= 8 && oc < 12) ? f2bfu(c2w[(oc * 8 + j) * 9 + t])
                                           : (unsigned short)0;
        b2f[s] = bb.v;
    }
    const float bias2 = (oc < 12) ? c2b[oc] : 0.0f;
    __syncthreads();

    // ---- conv2 via MFMA + fused maxpool -> h2 interior ----
    for (int h = 0; h < 2; ++h) {
        #pragma unroll
        for (int Yi = 0; Yi < 4; ++Yi) {
            int Y = wave * 4 + Yi;
            float m0 = -1e30f, m1 = -1e30f;
            #pragma unroll
            for (int half = 0; half < 2; ++half) {
                int y = 2 * Y + half;
                f32x4 acc = {bias2, bias2, bias2, bias2};
                #pragma unroll
                for (int s = 0; s < 3; ++s) {
                    int off = ((y + ky2[s]) * 34 + (h * 16 + mA + kx2[s])) * 8;
                    bf16x8 a = *(const bf16x8*)&h1[off];
                    acc = __builtin_amdgcn_mfma_f32_16x16x32_bf16(a, b2f[s], acc, 0, 0, 0);
                }
                m0 = fmaxf(m0, fmaxf(acc[0], acc[1]));
                m1 = fmaxf(m1, fmaxf(acc[2], acc[3]));
            }
            if (oc < 12) {
                int X0 = h * 8 + q * 2;
                h2[((Y + 1) * 18 + (X0 + 1)) * 16 + oc] = f2bfu(fmaxf(m0, 0.0f));
                h2[((Y + 1) * 18 + (X0 + 2)) * 16 + oc] = f2bfu(fmaxf(m1, 0.0f));
            }
        }
    }
    __syncthreads();

    // ---- conv3 via MFMA + relu + mean -> pooled[img][16] ----
    {
        const int hhalf = q & 1, tq = q >> 1;
        int ky3[5], kx3[5];
        bf16x8 b3f[5];
        #pragma unroll
        for (int s = 0; s < 5; ++s) {
            int slot = 2 * s + tq;
            int tt = (slot > 8) ? 4 : slot;
            ky3[s] = tt / 3; kx3[s] = tt % 3;
            union { unsigned short us[8]; bf16x8 v; } bb;
            #pragma unroll
            for (int j = 0; j < 8; ++j) {
                int ci = hhalf * 8 + j;
                bb.us[j] = (slot <= 8 && ci < 12) ? f2bfu(c3w[(oc * 12 + ci) * 9 + slot])
                                                  : (unsigned short)0;
            }
            b3f[s] = bb.v;
        }
        const float bias3 = c3b[oc];
        float psum = 0.0f;
        #pragma unroll
        for (int Yi = 0; Yi < 4; ++Yi) {
            int y = wave * 4 + Yi;
            f32x4 acc = {bias3, bias3, bias3, bias3};
            #pragma unroll
            for (int s = 0; s < 5; ++s) {
                int off = ((y + ky3[s]) * 18 + (mA + kx3[s])) * 16 + hhalf * 8;
                bf16x8 a = *(const bf16x8*)&h2[off];
                acc = __builtin_amdgcn_mfma_f32_16x16x32_bf16(a, b3f[s], acc, 0, 0, 0);
            }
            psum += fmaxf(acc[0], 0.0f) + fmaxf(acc[1], 0.0f)
                  + fmaxf(acc[2], 0.0f) + fmaxf(acc[3], 0.0f);
        }
        psum += __shfl_down(psum, 32);
        psum += __shfl_down(psum, 16);
        float* red = (float*)h1;
        if (lane < 16) red[lane * 4 + wave] = psum;
        __syncthreads();
        if (tid < 16) {
            float s = red[tid * 4] + red[tid * 4 + 1] + red[tid * 4 + 2] + red[tid * 4 + 3];
            pooled[(size_t)img * 16 + tid] = s * (1.0f / 256.0f);
        }
    }
}

// ---------------------------------------------------------------------------
// Kernel B: head (R7/R10 verbatim). 256-thr blocks, 4 waves, ONE WAVE PER ROW.
// ---------------------------------------------------------------------------
struct RowS {
    float ph[5][16], mt[5][16];
    float zc[5][20], zmh[5][12], zm[5][12];
    float p1h[5][24], h0[5][24];
    float archl[5][6], q[5][6];
    float center[5][24], coord[5][24], x0[5][24];
    float qkv[5][72];
    float attn[2][5][5];
    float amix[5][24], aout[5][24], x1[5][24];
    float ffh[5][48], ff2o[5][24], hset[5][24], mo[5][24];
    float pq[20], pdist[20];
    float relh[20][10], relo[20][10];
    float rmean[5][10], rmax[5][10];
    float sfeat[5][146];
    float s1h[5][40];
};

__global__ __launch_bounds__(256)
void head_kernel(const float* __restrict__ pooled,    // [B*5,16]
                 const float* __restrict__ meta,      // [B,5,16]
                 const float* __restrict__ enc_fc_w, const float* __restrict__ enc_fc_b,
                 const float* __restrict__ m1_w, const float* __restrict__ m1_b,
                 const float* __restrict__ m2_w, const float* __restrict__ m2_b,
                 const float* __restrict__ p1_w, const float* __restrict__ p1_b,
                 const float* __restrict__ p2_w, const float* __restrict__ p2_b,
                 const float* __restrict__ centers,
                 const float* __restrict__ arch_w, const float* __restrict__ arch_b,
                 const float* __restrict__ in_proj_w, const float* __restrict__ in_proj_b,
                 const float* __restrict__ out_proj_w, const float* __restrict__ out_proj_b,
                 const float* __restrict__ ln1_g, const float* __restrict__ ln1_b,
                 const float* __restrict__ ff1_w, const float* __restrict__ ff1_b,
                 const float* __restrict__ ff2_w, const float* __restrict__ ff2_b,
                 const float* __restrict__ ln2_g, const float* __restrict__ ln2_b,
                 const float* __restrict__ rel1_w, const float* __restrict__ rel1_b,
                 const float* __restrict__ rel2_w, const float* __restrict__ rel2_b,
                 const float* __restrict__ s1_w, const float* __restrict__ s1_b,
                 const float* __restrict__ s2_w, const float* __restrict__ s2_b,
                 float* __restrict__ out, int q_off, int Bb)
{
    __shared__ RowS S[4];

    const int tid  = threadIdx.x;
    const int wid  = tid >> 6;
    const int lane = tid & 63;
    const int row  = blockIdx.x * 4 + wid;
    if (row >= Bb) return;

    RowS& H = S[wid];

    for (int i = lane; i < 80; i += 64) ((float*)H.ph)[i] = pooled[(size_t)row * 80 + i];
    for (int i = lane; i < 80; i += 64) ((float*)H.mt)[i] = meta[(size_t)row * 80 + i];

    for (int idx = lane; idx < 100; idx += 64) {
        int n = idx / 20, o = idx % 20;
        float a = enc_fc_b[o];
        #pragma unroll
        for (int k = 0; k < 16; ++k) a += H.ph[n][k] * enc_fc_w[o * 16 + k];
        H.zc[n][o] = a;
    }
    for (int idx = lane; idx < 60; idx += 64) {
        int n = idx / 12, o = idx % 12;
        float a = m1_b[o];
        #pragma unroll
        for (int k = 0; k < 16; ++k) a += H.mt[n][k] * m1_w[o * 16 + k];
        H.zmh[n][o] = fmaxf(a, 0.0f);
    }
    for (int idx = lane; idx < 60; idx += 64) {
        int n = idx / 12, o = idx % 12;
        float a = m2_b[o];
        #pragma unroll
        for (int k = 0; k < 12; ++k) a += H.zmh[n][k] * m2_w[o * 12 + k];
        H.zm[n][o] = a;
    }
    for (int idx = lane; idx < 120; idx += 64) {
        int n = idx / 24, o = idx % 24;
        float a = p1_b[o];
        #pragma unroll
        for (int k = 0; k < 20; ++k) a += H.zc[n][k] * p1_w[o * 32 + k];
        #pragma unroll
        for (int k = 0; k < 12; ++k) a += H.zm[n][k] * p1_w[o * 32 + 20 + k];
        H.p1h[n][o] = fmaxf(a, 0.0f);
    }
    for (int idx = lane; idx < 120; idx += 64) {
        int n = idx / 24, o = idx % 24;
        float a = p2_b[o];
        #pragma unroll
        for (int k = 0; k < 24; ++k) a += H.p1h[n][k] * p2_w[o * 24 + k];
        H.h0[n][o] = a;
    }
    for (int idx = lane; idx < 30; idx += 64) {
        int n = idx / 6, o = idx % 6;
        float a = arch_b[o];
        #pragma unroll
        for (int k = 0; k < 24; ++k) a += H.h0[n][k] * arch_w[o * 24 + k];
        H.archl[n][o] = a;
    }
    if (lane < 5) {
        int n = lane;
        float m = H.archl[n][0];
        #pragma unroll
        for (int k = 1; k < 6; ++k) m = fmaxf(m, H.archl[n][k]);
        float e[6], s = 0.0f;
        #pragma unroll
        for (int k = 0; k < 6; ++k) { e[k] = __expf(H.archl[n][k] - m); s += e[k]; }
        float inv = 1.0f / s;
        #pragma unroll
        for (int k = 0; k < 6; ++k) H.q[n][k] = e[k] * inv;
    }
    for (int idx = lane; idx < 120; idx += 64) {
        int n = idx / 24, d = idx % 24;
        float a = 0.0f;
        #pragma unroll
        for (int k = 0; k < 6; ++k) a += H.q[n][k] * centers[k * 24 + d];
        H.center[n][d] = a;
        H.coord[n][d] = H.h0[n][d] - a;
        H.x0[n][d] = H.h0[n][d] + a;
    }
    for (int idx = lane; idx < 360; idx += 64) {
        int n = idx / 72, o = idx % 72;
        float a = in_proj_b[o];
        #pragma unroll
        for (int k = 0; k < 24; ++k) a += H.x0[n][k] * in_proj_w[o * 24 + k];
        H.qkv[n][o] = a;
    }
    if (lane < 10) {
        int h = lane / 5, i = lane % 5;
        const float scale = 0.28867513459481287f;  // 1/sqrt(12)
        float sc[5], m = -1e30f;
        for (int j = 0; j < 5; ++j) {
            float a = 0.0f;
            #pragma unroll
            for (int d = 0; d < 12; ++d) a += H.qkv[i][h * 12 + d] * H.qkv[j][24 + h * 12 + d];
            sc[j] = a * scale;
            m = fmaxf(m, sc[j]);
        }
        float s = 0.0f;
        #pragma unroll
        for (int j = 0; j < 5; ++j) { sc[j] = __expf(sc[j] - m); s += sc[j]; }
        float inv = 1.0f / s;
        #pragma unroll
        for (int j = 0; j < 5; ++j) H.attn[h][i][j] = sc[j] * inv;
    }
    for (int idx = lane; idx < 120; idx += 64) {
        int i = idx / 24, o = idx % 24;
        int h = o / 12, d = o % 12;
        float a = 0.0f;
        #pragma unroll
        for (int j = 0; j < 5; ++j) a += H.attn[h][i][j] * H.qkv[j][48 + h * 12 + d];
        H.amix[i][o] = a;
    }
    for (int idx = lane; idx < 120; idx += 64) {
        int n = idx / 24, o = idx % 24;
        float a = out_proj_b[o];
        #pragma unroll
        for (int k = 0; k < 24; ++k) a += H.amix[n][k] * out_proj_w[o * 24 + k];
        H.aout[n][o] = H.x0[n][o] + a;
    }
    if (lane < 5) {
        int n = lane;
        float m = 0.0f;
        #pragma unroll
        for (int k = 0; k < 24; ++k) m += H.aout[n][k];
        m *= (1.0f / 24.0f);
        float v = 0.0f;
        #pragma unroll
        for (int k = 0; k < 24; ++k) { float d = H.aout[n][k] - m; v += d * d; }
        v *= (1.0f / 24.0f);
        float inv = 1.0f / sqrtf(v + 1e-5f);
        #pragma unroll
        for (int k = 0; k < 24; ++k)
            H.x1[n][k] = (H.aout[n][k] - m) * inv * ln1_g[k] + ln1_b[k];
    }
    for (int idx = lane; idx < 240; idx += 64) {
        int n = idx / 48, o = idx % 48;
        float a = ff1_b[o];
        #pragma unroll
        for (int k = 0; k < 24; ++k) a += H.x1[n][k] * ff1_w[o * 24 + k];
        H.ffh[n][o] = fmaxf(a, 0.0f);
    }
    for (int idx = lane; idx < 120; idx += 64) {
        int n = idx / 24, o = idx % 24;
        float a = ff2_b[o];
        #pragma unroll
        for (int k = 0; k < 48; ++k) a += H.ffh[n][k] * ff2_w[o * 48 + k];
        H.ff2o[n][o] = H.x1[n][o] + a;
    }
    if (lane < 5) {
        int n = lane;
        float m = 0.0f;
        #pragma unroll
        for (int k = 0; k < 24; ++k) m += H.ff2o[n][k];
        m *= (1.0f / 24.0f);
        float v = 0.0f;
        #pragma unroll
        for (int k = 0; k < 24; ++k) { float d = H.ff2o[n][k] - m; v += d * d; }
        v *= (1.0f / 24.0f);
        float inv = 1.0f / sqrtf(v + 1e-5f);
        #pragma unroll
        for (int k = 0; k < 24; ++k)
            H.hset[n][k] = (H.ff2o[n][k] - m) * inv * ln2_g[k] + ln2_b[k];
    }
    for (int idx = lane; idx < 120; idx += 64) {
        int n = idx / 24, d = idx % 24;
        float s = H.hset[0][d] + H.hset[1][d] + H.hset[2][d] + H.hset[3][d] + H.hset[4][d];
        H.mo[n][d] = (s - H.hset[n][d]) * 0.25f;
    }
    if (lane < 20) {
        int i = lane / 4, jj = lane % 4;
        int j = jj + (jj >= i ? 1 : 0);
        float qo = 0.0f;
        #pragma unroll
        for (int k = 0; k < 6; ++k) qo += H.q[i][k] * H.q[j][k];
        H.pq[lane] = qo;
        float d2 = 0.0f;
        #pragma unroll
        for (int k = 0; k < 24; ++k) { float d = H.coord[i][k] - H.coord[j][k]; d2 += d * d; }
        H.pdist[lane] = (d2 > 0.0f) ? sqrtf(d2) : 0.0f;
    }
    for (int idx = lane; idx < 200; idx += 64) {
        int p = idx / 10, c = idx % 10;
        int i = p / 4, jj = p % 4;
        int j = jj + (jj >= i ? 1 : 0);
        float a = rel1_b[c];
        const float* wr = rel1_w + c * 74;
        #pragma unroll
        for (int k = 0; k < 24; ++k) a += H.hset[i][k] * wr[k];
        #pragma unroll
        for (int k = 0; k < 24; ++k) a += H.hset[j][k] * wr[24 + k];
        #pragma unroll
        for (int k = 0; k < 24; ++k) a += fabsf(H.coord[i][k] - H.coord[j][k]) * wr[48 + k];
        a += H.pq[p] * wr[72];
        a += H.pdist[p] * wr[73];
        H.relh[p][c] = fmaxf(a, 0.0f);
    }
    for (int idx = lane; idx < 200; idx += 64) {
        int p = idx / 10, c = idx % 10;
        float a = rel2_b[c];
        #pragma unroll
        for (int k = 0; k < 10; ++k) a += H.relh[p][k] * rel2_w[c * 10 + k];
        H.relo[p][c] = fmaxf(a, 0.0f);
    }
    for (int idx = lane; idx < 50; idx += 64) {
        int i = idx / 10, c = idx % 10;
        float s = 0.0f, m = -1e30f;
        #pragma unroll
        for (int jj = 0; jj < 4; ++jj) {
            float v = H.relo[i * 4 + jj][c];
            s += v; m = fmaxf(m, v);
        }
        H.rmean[i][c] = s * 0.25f;
        H.rmax[i][c] = m;
    }
    for (int idx = lane; idx < 730; idx += 64) {
        int n = idx / 146, k = idx % 146;
        float v;
        if (k < 24)       v = H.h0[n][k];
        else if (k < 48)  v = H.hset[n][k - 24];
        else if (k < 72)  v = H.center[n][k - 48];
        else if (k < 96)  v = H.coord[n][k - 72];
        else if (k < 120) v = fabsf(H.hset[n][k - 96] - H.mo[n][k - 96]);
        else if (k < 130) v = H.rmean[n][k - 120];
        else if (k < 140) v = H.rmax[n][k - 130];
        else              v = H.q[n][k - 140];
        H.sfeat[n][k] = v;
    }
    for (int idx = lane; idx < 200; idx += 64) {
        int n = idx / 40, o = idx % 40;
        float a = s1_b[o];
        #pragma unroll 8
        for (int k = 0; k < 146; ++k) a += H.sfeat[n][k] * s1_w[o * 146 + k];
        H.s1h[n][o] = fmaxf(a, 0.0f);
    }
    if (lane < 5) {
        int n = lane;
        float a = s2_b[0];
        #pragma unroll
        for (int k = 0; k < 40; ++k) a += H.s1h[n][k] * s2_w[k];
        out[(size_t)row * 5 + n] = a;
    }
    if (lane < 30) {
        out[q_off + (size_t)row * 30 + lane] = H.q[lane / 6][lane % 6];
    }
}

extern "C" void kernel_launch(void* const* d_in, const int* in_sizes, int n_in,
                              void* d_out, int out_size, void* d_ws, size_t ws_size,
                              hipStream_t stream) {
    const int BN = in_sizes[0] / (64 * 64);   // B*5
    const int Bb = BN / 5;                    // B

    float* pooled = (float*)d_ws;             // [BN][16] fp32

    cnn_panel_kernel<<<BN, 256, 0, stream>>>(
        (const float*)d_in[0],
        (const float*)d_in[2], (const float*)d_in[3],
        (const float*)d_in[4], (const float*)d_in[5],
        (const float*)d_in[6], (const float*)d_in[7],
        pooled);

    head_kernel<<<(Bb + 3) / 4, 256, 0, stream>>>(
        pooled, (const float*)d_in[1],
        (const float*)d_in[8], (const float*)d_in[9],
        (const float*)d_in[10], (const float*)d_in[11],
        (const float*)d_in[12], (const float*)d_in[13],
        (const float*)d_in[14], (const float*)d_in[15],
        (const float*)d_in[16], (const float*)d_in[17],
        (const float*)d_in[18],
        (const float*)d_in[19], (const float*)d_in[20],
        (const float*)d_in[21], (const float*)d_in[22],
        (const float*)d_in[23], (const float*)d_in[24],
        (const float*)d_in[25], (const float*)d_in[26],
        (const float*)d_in[27], (const float*)d_in[28],
        (const float*)d_in[29], (const float*)d_in[30],
        (const float*)d_in[31], (const float*)d_in[32],
        (const float*)d_in[33], (const float*)d_in[34],
        (const float*)d_in[35], (const float*)d_in[36],
        (const float*)d_in[37], (const float*)d_in[38],
        (const float*)d_in[39], (const float*)d_in[40],
        (float*)d_out, BN, Bb);
}